// Round 6
// baseline (361.117 us; speedup 1.0000x reference)
//
#include <hip/hip_runtime.h>
#include <math.h>

#define NROWS 131072   // 32*64*64
#define CDIM  64
#define NCODE 1024
#define NT    (NCODE / 16)
#define MARGIN 0.15f   // > 2*max screening err (~4e-2); flag rate ~2%
#define LOSS_SCALE (1.25f / ((float)NROWS * (float)CDIM))

typedef _Float16 half8 __attribute__((ext_vector_type(8)));
typedef _Float16 half4 __attribute__((ext_vector_type(4)));
typedef float    f32x4 __attribute__((ext_vector_type(4)));

// d_ws layout: [0,4096) e2 fp32[1024] ; [4096, 4096+128K) eh f16[1024*64]
#define WS_EH_OFF 4096

// prep: codebook fp32 norms + f16 conversion; also zeroes the loss scalar.
__global__ __launch_bounds__(256) void vq_prep(
    const float* __restrict__ embs, float* __restrict__ e2,
    unsigned short* __restrict__ eh_u, float* __restrict__ loss)
{
    if (blockIdx.x == 0 && threadIdx.x == 0) *loss = 0.0f;
    _Float16* eh = (_Float16*)eh_u;
    const int k = blockIdx.x * 256 + threadIdx.x;
    const float* ep = embs + (size_t)k * CDIM;
    float s = 0.0f;
    #pragma unroll
    for (int d = 0; d < CDIM; d += 4) {
        const float4 e4 = *(const float4*)(ep + d);
        s = fmaf(e4.x, e4.x, s);
        s = fmaf(e4.y, e4.y, s);
        s = fmaf(e4.z, e4.z, s);
        s = fmaf(e4.w, e4.w, s);
        half4 h;
        h[0] = (_Float16)e4.x; h[1] = (_Float16)e4.y;
        h[2] = (_Float16)e4.z; h[3] = (_Float16)e4.w;
        *(half4*)(eh + (size_t)k * CDIM + d) = h;
    }
    e2[k] = s;
}

// Single main kernel. Block = 4 waves, 64 rows (16 rows / wave = 1 M-tile ->
// 2048 blocks = 8 waves/SIMD). Screening: dist = e2[n] + (-2z)_f16 . e_f16 via
// 2 MFMA per 16-code tile, best+second tracked (v_med3). Rows whose screened
// gap < MARGIN are re-resolved exactly in fp32 by the whole block before the
// epilogue writes zq and accumulates the loss — no second kernel needed.
__global__ __launch_bounds__(256) void vq_main(
    const float* __restrict__ ze, const float* __restrict__ embs,
    const float* __restrict__ e2, const unsigned short* __restrict__ eh_u,
    float* __restrict__ out, float* __restrict__ loss)
{
    __shared__ unsigned s_idx[64];
    __shared__ int s_flist[64];
    __shared__ int s_fcnt;
    __shared__ float s_rb[4];
    __shared__ int   s_ri[4];
    __shared__ float s_red[4];

    const int tid  = threadIdx.x;
    const int lane = tid & 63;
    const int wv   = tid >> 6;
    const int col  = lane & 15;
    const int quad = lane >> 4;
    if (tid == 0) s_fcnt = 0;
    const int rbase = blockIdx.x * 64 + wv * 16;

    // --- A fragment: f16(-2z), A[m=col][k=quad*8+j] per khalf ---
    half8 ah[2];
    const float* zp = ze + (size_t)(rbase + col) * CDIM + quad * 8;
    #pragma unroll
    for (int h = 0; h < 2; ++h) {
        const float4 v0 = *(const float4*)(zp + h * 32);
        const float4 v1 = *(const float4*)(zp + h * 32 + 4);
        ah[h][0] = (_Float16)(-2.0f * v0.x); ah[h][1] = (_Float16)(-2.0f * v0.y);
        ah[h][2] = (_Float16)(-2.0f * v0.z); ah[h][3] = (_Float16)(-2.0f * v0.w);
        ah[h][4] = (_Float16)(-2.0f * v1.x); ah[h][5] = (_Float16)(-2.0f * v1.y);
        ah[h][6] = (_Float16)(-2.0f * v1.z); ah[h][7] = (_Float16)(-2.0f * v1.w);
    }
    __syncthreads();   // s_fcnt init visible

    float bb[4] = {INFINITY, INFINITY, INFINITY, INFINITY};
    float ss[4] = {INFINITY, INFINITY, INFINITY, INFINITY};
    int   tt[4] = {0, 0, 0, 0};

    const _Float16* eh  = (const _Float16*)eh_u;
    const _Float16* ehc = eh + (size_t)col * CDIM + quad * 8;  // B^T: row=col, k=quad*8+j

    // software pipeline: prefetch next tile's B + e2 over current bookkeeping
    float ev = e2[col];
    half8 b0 = *(const half8*)(ehc);
    half8 b1 = *(const half8*)(ehc + 32);

    #pragma unroll 2
    for (int nt = 0; nt < NT - 1; ++nt) {
        const float evn = e2[(nt + 1) * 16 + col];
        const half8 b0n = *(const half8*)(ehc + (size_t)(nt + 1) * 16 * CDIM);
        const half8 b1n = *(const half8*)(ehc + (size_t)(nt + 1) * 16 * CDIM + 32);
        f32x4 acc = {ev, ev, ev, ev};
        acc = __builtin_amdgcn_mfma_f32_16x16x32_f16(ah[0], b0, acc, 0, 0, 0);
        acc = __builtin_amdgcn_mfma_f32_16x16x32_f16(ah[1], b1, acc, 0, 0, 0);
        #pragma unroll
        for (int r = 0; r < 4; ++r) {
            const float u = acc[r];
            tt[r] = (u < bb[r]) ? nt : tt[r];
            ss[r] = __builtin_amdgcn_fmed3f(ss[r], bb[r], u);  // new second-best
            bb[r] = fminf(bb[r], u);
        }
        ev = evn; b0 = b0n; b1 = b1n;
    }
    {
        f32x4 acc = {ev, ev, ev, ev};
        acc = __builtin_amdgcn_mfma_f32_16x16x32_f16(ah[0], b0, acc, 0, 0, 0);
        acc = __builtin_amdgcn_mfma_f32_16x16x32_f16(ah[1], b1, acc, 0, 0, 0);
        #pragma unroll
        for (int r = 0; r < 4; ++r) {
            const float u = acc[r];
            tt[r] = (u < bb[r]) ? (NT - 1) : tt[r];
            ss[r] = __builtin_amdgcn_fmed3f(ss[r], bb[r], u);
            bb[r] = fminf(bb[r], u);
        }
    }

    // --- cross-lane (16 cols) first-min + second reduce; row m = quad*4+r ---
    #pragma unroll
    for (int r = 0; r < 4; ++r) {
        float b = bb[r], s = ss[r];
        int   i = tt[r] * 16 + col;
        #pragma unroll
        for (int off = 1; off < 16; off <<= 1) {
            const float ob = __shfl_xor(b, off, 64);
            const float os = __shfl_xor(s, off, 64);
            const int   oi = __shfl_xor(i, off, 64);
            s = fminf(fminf(s, os), fmaxf(b, ob));
            const bool take = (ob < b) || (ob == b && oi < i);
            b = take ? ob : b;
            i = take ? oi : i;
        }
        if (col == 0) {
            const int lrow = wv * 16 + quad * 4 + r;
            s_idx[lrow] = (unsigned)i;
            if (s - b < MARGIN) {
                const int p = atomicAdd(&s_fcnt, 1);
                s_flist[p] = lrow;
            }
        }
    }
    __syncthreads();

    // --- in-block exact fp32 re-resolution of flagged rows (~2% of rows) ---
    const int nflag = s_fcnt;
    for (int f = 0; f < nflag; ++f) {
        const int lrow = s_flist[f];
        const float* zr = ze + (size_t)(blockIdx.x * 64 + lrow) * CDIM;  // uniform -> broadcast
        const int c0 = tid * 4;   // 4 codes per thread, ascending
        float a0 = e2[c0], a1 = e2[c0 + 1], a2 = e2[c0 + 2], a3 = e2[c0 + 3];
        #pragma unroll
        for (int d = 0; d < CDIM; d += 4) {
            const float4 zv = *(const float4*)(zr + d);
            const float m0 = -2.0f * zv.x, m1 = -2.0f * zv.y;
            const float m2 = -2.0f * zv.z, m3 = -2.0f * zv.w;
            const float4 e0 = *(const float4*)(embs + (size_t)(c0 + 0) * CDIM + d);
            const float4 e1 = *(const float4*)(embs + (size_t)(c0 + 1) * CDIM + d);
            const float4 e2v = *(const float4*)(embs + (size_t)(c0 + 2) * CDIM + d);
            const float4 e3 = *(const float4*)(embs + (size_t)(c0 + 3) * CDIM + d);
            a0 = fmaf(m0, e0.x, fmaf(m1, e0.y, fmaf(m2, e0.z, fmaf(m3, e0.w, a0))));
            a1 = fmaf(m0, e1.x, fmaf(m1, e1.y, fmaf(m2, e1.z, fmaf(m3, e1.w, a1))));
            a2 = fmaf(m0, e2v.x, fmaf(m1, e2v.y, fmaf(m2, e2v.z, fmaf(m3, e2v.w, a2))));
            a3 = fmaf(m0, e3.x, fmaf(m1, e3.y, fmaf(m2, e3.z, fmaf(m3, e3.w, a3))));
        }
        float bd = a0; int bi = c0;
        if (a1 < bd) { bd = a1; bi = c0 + 1; }
        if (a2 < bd) { bd = a2; bi = c0 + 2; }
        if (a3 < bd) { bd = a3; bi = c0 + 3; }
        #pragma unroll
        for (int off = 1; off < 64; off <<= 1) {
            const float ob = __shfl_xor(bd, off, 64);
            const int   oi = __shfl_xor(bi, off, 64);
            if (ob < bd || (ob == bd && oi < bi)) { bd = ob; bi = oi; }
        }
        if (lane == 0) { s_rb[wv] = bd; s_ri[wv] = bi; }
        __syncthreads();
        if (tid == 0) {
            float fb = s_rb[0]; int fi = s_ri[0];
            #pragma unroll
            for (int j = 1; j < 4; ++j)
                if (s_rb[j] < fb || (s_rb[j] == fb && s_ri[j] < fi)) { fb = s_rb[j]; fi = s_ri[j]; }
            s_idx[lrow] = (unsigned)fi;
        }
        __syncthreads();
    }

    // --- epilogue: gather winner, write zq, loss (coalesced 16-float slices) ---
    const int rr = tid >> 2;
    const int q  = tid & 3;
    const unsigned widx = s_idx[rr];
    const size_t obase = (size_t)(blockIdx.x * 64 + rr) * CDIM + q * 16;
    const float* ep = embs + (size_t)widx * CDIM + q * 16;
    const float* zr = ze + obase;
    float* op = out + obase;
    float psum = 0.0f;
    #pragma unroll
    for (int d = 0; d < 16; d += 4) {
        const float4 e4 = *(const float4*)(ep + d);
        *(float4*)(op + d) = e4;
        const float4 zv = *(const float4*)(zr + d);
        const float f0 = e4.x - zv.x;
        const float f1 = e4.y - zv.y;
        const float f2 = e4.z - zv.z;
        const float f3 = e4.w - zv.w;
        psum = fmaf(f0, f0, psum);
        psum = fmaf(f1, f1, psum);
        psum = fmaf(f2, f2, psum);
        psum = fmaf(f3, f3, psum);
    }
    #pragma unroll
    for (int off = 32; off > 0; off >>= 1)
        psum += __shfl_down(psum, off, 64);
    if (lane == 0) s_red[wv] = psum;
    __syncthreads();
    if (tid == 0) {
        const float b = (s_red[0] + s_red[1]) + (s_red[2] + s_red[3]);
        atomicAdd(loss, b * LOSS_SCALE);
    }
}

extern "C" void kernel_launch(void* const* d_in, const int* in_sizes, int n_in,
                              void* d_out, int out_size, void* d_ws, size_t ws_size,
                              hipStream_t stream) {
    const float* ze   = (const float*)d_in[0];   // [32,64,64,64] fp32
    const float* embs = (const float*)d_in[1];   // [1024,64] fp32
    float* out  = (float*)d_out;                 // zq_st (8388608 floats) then loss (1)
    float* loss = out + (out_size - 1);

    float*          e2 = (float*)d_ws;
    unsigned short* eh = (unsigned short*)((char*)d_ws + WS_EH_OFF);

    vq_prep<<<NCODE / 256, 256, 0, stream>>>(embs, e2, eh, loss);
    vq_main<<<NROWS / 64, 256, 0, stream>>>(ze, embs, e2, eh, out, loss);
}